// Round 11
// baseline (179.797 us; speedup 1.0000x reference)
//
#include <hip/hip_runtime.h>

// Newton-Schulz batched inverse, 1024 x (128x128) fp32.
// R17: R16's DPP 4x4 lane-transpose epilogue with the block-exchange bug
// fixed. The 4x4 u16 transpose over a lane quad is [[A,B],[C,D]] ->
// [[A^T,C^T],[B^T,D^T]]: lanes {0,1} keep lo(A) and take mhi from the
// xor2-neighbor's lo (C); lanes {2,3} take mlo from the neighbor's hi (B)
// and keep hi(D). R16 had the mhi select inverted (kept B / fetched A),
// scrambling xcm's off-diagonal 2x2 sub-blocks -> 3.2e-3. Also replaced
// v_perm_b32 with explicit shift/mask (no builtin-semantics risk).
// Values + destinations now provably identical to the passing R15 ->
// absmax exactly 9.155273e-5. Everything else unchanged (512 thr, VGPR
// ~108 no-spill, wfrag in regs, SROW=132, shuffle-tree norms).

#define NN 128

typedef __attribute__((ext_vector_type(8))) short bf16x8;
typedef __attribute__((ext_vector_type(16))) float f32x16;
typedef __attribute__((ext_vector_type(4))) float f32x4;
typedef __attribute__((ext_vector_type(4))) unsigned short us4;
typedef __attribute__((ext_vector_type(2))) unsigned int u32x2;

// LDS layout (bytes):
#define XRM_OFF   0        // X row-major bf16                 32768
#define XCM_OFF   32768    // X col-major bf16                 32768
#define SCR_OFF   65536    // T col-major bf16                 32768
#define STAGE_OFF 65536    // fp32 W stage [65536,133120); dead before scr use
#define RED_OFF   0        // 256 floats in xrm region during phase 0 only
#define LDS_BYTES 133120
#define SROW 132           // stage row pitch in floats (528B = 16B mod 128B)

__device__ __forceinline__ unsigned short f2bf(float f) {
  unsigned u = __float_as_uint(f);
  return (unsigned short)((u + 0x7FFFu + ((u >> 16) & 1u)) >> 16);  // RNE
}
__device__ __forceinline__ float bf2f(unsigned short h) {
  return __uint_as_float(((unsigned)h) << 16);
}
__device__ __forceinline__ f32x16 zero16() {
  f32x16 z;
#pragma unroll
  for (int i = 0; i < 16; ++i) z[i] = 0.0f;
  return z;
}
// XOR swizzle in a [R][128] bf16 buffer: 8-elem granule g -> g ^ (R&15).
__device__ __forceinline__ int swz8(int R, int k0) {  // k0 % 8 == 0
  return R * 128 + (((k0 >> 3) ^ (R & 15)) << 3);
}
__device__ __forceinline__ int swz4(int R, int c0) {  // c0 % 4 == 0
  return R * 128 + ((((c0 >> 3) ^ (R & 15)) << 3) | (c0 & 7));
}

__global__ void __launch_bounds__(512)
__attribute__((amdgpu_waves_per_eu(2, 2)))
ns_inverse_kernel(const float* __restrict__ Wglob, const int* __restrict__ nIt,
                  float* __restrict__ outglob) {
  extern __shared__ char lds[];
  unsigned short* xrm = (unsigned short*)(lds + XRM_OFF);
  unsigned short* xcm = (unsigned short*)(lds + XCM_OFF);
  unsigned short* scr = (unsigned short*)(lds + SCR_OFF);
  float* stage = (float*)(lds + STAGE_OFF);
  float* red   = (float*)(lds + RED_OFF);

  const int b = blockIdx.x;
  const float* Wg = Wglob + (size_t)b * (NN * NN);
  float* outg = outglob + (size_t)b * (NN * NN);
  const int t = threadIdx.x;      // 0..511
  const int lane = t & 63;
  const int wv = t >> 6;          // 0..7
  const int l31 = lane & 31;
  const int half = lane >> 5;
  const int s = wv & 3;           // strip: W rows (mm1 A) / X' rows (mm2 B, epi)
  const int g = wv >> 2;          // band pair: tiles v0=2g, v1=2g+1
  const int v0 = 2 * g, v1 = 2 * g + 1;
  const int niters = nIt[0];

  // ---- phase 0: stage W fp32 into padded-pitch LDS (only global read) ----
  {
    const f32x4* src = (const f32x4*)Wg;
#pragma unroll
    for (int i = 0; i < 8; ++i) {
      int idx = t + 512 * i;          // f32x4 index, 4096 total
      int r = idx >> 5, cp = idx & 31;
      f32x4 val = src[idx];
      *(f32x4*)(stage + r * SROW + 4 * cp) = val;
    }
  }
  __syncthreads();

  // ---- norms (red lives in xrm region; xrm filled later) ----
  if (t < 128) {            // row sums (rotated start; serial order preserved)
    float ssum = 0.f;
    for (int jj = 0; jj < NN; ++jj) { int j = (jj + t) & 127; ssum += fabsf(stage[t * SROW + j]); }
    red[t] = ssum;
  } else if (t < 256) {     // col sums (serial order preserved)
    int c = t - 128;
    float ssum = 0.f;
    for (int i = 0; i < NN; ++i) ssum += fabsf(stage[i * SROW + c]);
    red[128 + c] = ssum;
  }
  __syncthreads();
  // Wave-parallel max reduce (fmax exactly associative+commutative).
  float mA = fmaxf(red[lane], red[lane + 64]);          // ninf over red[0..128)
  float mB = fmaxf(red[128 + lane], red[192 + lane]);   // n1 over red[128..256)
#pragma unroll
  for (int k = 32; k >= 1; k >>= 1) {
    mA = fmaxf(mA, __shfl_xor(mA, k, 64));
    mB = fmaxf(mB, __shfl_xor(mB, k, 64));
  }
  const float ninf = mA;
  const float n1 = mB;
  const float scale = 1.0f / (n1 * ninf);
  __syncthreads();   // everyone has scale; red region may be overwritten now

  // ---- W row fragments to registers (bf16(W), identical bits to R6 wrm) ----
  const int pX = 32 * s + l31;    // lane-owned W row / X/X' row
  bf16x8 wfrag[8];
#pragma unroll
  for (int ks = 0; ks < 8; ++ks) {
    const float* src = stage + pX * SROW + 16 * ks + 8 * half;
    f32x4 f0 = *(const f32x4*)(src);
    f32x4 f1 = *(const f32x4*)(src + 4);
    bf16x8 wb;
#pragma unroll
    for (int e = 0; e < 4; ++e) {
      wb[e]     = (short)f2bf(f0[e]);
      wb[4 + e] = (short)f2bf(f1[e]);
    }
    wfrag[ks] = wb;
  }

  // ---- fills from stage (same values/locations as R6/R14) ----
  // xcm row r = X0 col r = W row r * scale
  {
    const int r = t >> 2;               // 0..127
    const int c0 = (t & 3) * 32;        // 32 cols per thread
#pragma unroll
    for (int h = 0; h < 8; ++h) {
      f32x4 a = *(const f32x4*)(stage + r * SROW + c0 + 4 * h);
      us4 hx;
#pragma unroll
      for (int i = 0; i < 4; ++i) hx[i] = f2bf(a[i] * scale);
      *(us4*)(xcm + swz4(r, c0 + 4 * h)) = hx;
    }
  }
  // xrm row r = X0 row r = W col r * scale (LDS transpose from stage)
  {
    const int r = t & 127;
    const int kc = (t >> 7) * 32;       // 4 groups x 32 cols
#pragma unroll
    for (int j4 = 0; j4 < 8; ++j4) {
      int c0 = kc + 4 * j4;
      us4 h4;
#pragma unroll
      for (int i = 0; i < 4; ++i) h4[i] = f2bf(stage[(c0 + i) * SROW + r] * scale);
      *(us4*)(xrm + swz4(r, c0)) = h4;
    }
  }
  __syncthreads();   // stage dead from here; scr region free

  // ---- epilogue transpose constants (lane quads = transpose groups) ----
  const bool oddlane = (lane & 1) != 0;
  const bool swapblk = (lane & 2) != 0;
  const int p0 = 32 * s + (l31 & ~3);   // quad's X'-row block (xcm col base)
  const int jj = lane & 3;

  // ---------------- iterations: X' = 2X - X(WX) ----------------
  const int rv0 = 32 * v0 + l31;   // lane-owned xcm/scr rows (T cols)
  const int rv1 = 32 * v1 + l31;
  for (int it = 0; it < niters; ++it) {
    const bool last = (it == niters - 1);

    // ---- mm1: T tiles (s,v0) and (s,v1): A=wfrag (regs), B=xcm ----
#pragma unroll
    for (int i2 = 0; i2 < 2; ++i2) {
      const int rv = i2 ? rv1 : rv0;
      f32x16 tt = zero16();
#pragma unroll
      for (int ks = 0; ks < 8; ++ks) {
        int k0 = ks * 16 + half * 8;
        bf16x8 bv = *(const bf16x8*)(xcm + swz8(rv, k0));
        tt = __builtin_amdgcn_mfma_f32_32x32x16_bf16(wfrag[ks], bv, tt, 0, 0, 0);
      }
      // write T tile into scr (T col-major): scr row rv, cols = T rows strip s
#pragma unroll
      for (int q = 0; q < 4; ++q) {
        us4 h4;
#pragma unroll
        for (int i = 0; i < 4; ++i) h4[i] = f2bf(tt[4 * q + i]);
        *(us4*)(scr + swz4(rv, 32 * s + 8 * q + 4 * half)) = h4;
      }
    }
    __syncthreads();   // B1: full T assembled

    // ---- mm2: two (X@T)^T tiles; B-frag (xrm row pX) shared ----
    f32x16 acc0 = zero16(), acc1 = zero16();
#pragma unroll
    for (int ks = 0; ks < 8; ++ks) {
      int k0 = ks * 16 + half * 8;
      bf16x8 bv = *(const bf16x8*)(xrm + swz8(pX, k0));    // old X row (shared)
      bf16x8 a0 = *(const bf16x8*)(scr + swz8(rv0, k0));   // T col-major rows
      bf16x8 a1 = *(const bf16x8*)(scr + swz8(rv1, k0));
      acc0 = __builtin_amdgcn_mfma_f32_32x32x16_bf16(a0, bv, acc0, 0, 0, 0);
      acc1 = __builtin_amdgcn_mfma_f32_32x32x16_bf16(a1, bv, acc1, 0, 0, 0);
    }
    __syncthreads();   // B2: all scr + xrm reads complete before overwrite

    // ---- epilogue: X'[pX][32v + m] = 2X - (X@T), both bands ----
#pragma unroll
    for (int i2 = 0; i2 < 2; ++i2) {
      const int vb = i2 ? v1 : v0;
#pragma unroll
      for (int q = 0; q < 4; ++q) {
        int c0m = 32 * vb + 8 * q + 4 * half;
        int offr = swz4(pX, c0m);
        us4 xh4 = *(const us4*)(xrm + offr);
        f32x4 vv;
#pragma unroll
        for (int i = 0; i < 4; ++i)
          vv[i] = 2.0f * bf2f(xh4[i]) - (i2 ? acc1[4 * q + i] : acc0[4 * q + i]);
        if (last) {
          *(f32x4*)(outg + pX * NN + c0m) = vv;
        } else {
          us4 h4;
#pragma unroll
          for (int i = 0; i < 4; ++i) h4[i] = f2bf(vv[i]);
          *(us4*)(xrm + offr) = h4;          // X' row-major (vector, as before)
          // X' col-major via in-register 4x4 u16 lane-quad transpose.
          // Quad = [[A,B],[C,D]] (2x2 blocks of 2x2 u16). Transpose:
          // lanes{0,1}: mlo=lo(A), mhi=xor2-neighbor lo(C);
          // lanes{2,3}: mlo=xor2-neighbor hi(B), mhi=hi(D).   [R16 bug fixed]
          u32x2 d = __builtin_bit_cast(u32x2, h4);
          unsigned lo = d.x, hi = d.y;
          unsigned p2lo = (unsigned)__builtin_amdgcn_mov_dpp((int)lo, 0x4E, 0xf, 0xf, false);
          unsigned p2hi = (unsigned)__builtin_amdgcn_mov_dpp((int)hi, 0x4E, 0xf, 0xf, false);
          unsigned mlo = swapblk ? p2hi : lo;
          unsigned mhi = swapblk ? hi   : p2lo;
          unsigned p1lo = (unsigned)__builtin_amdgcn_mov_dpp((int)mlo, 0xB1, 0xf, 0xf, false);
          unsigned p1hi = (unsigned)__builtin_amdgcn_mov_dpp((int)mhi, 0xB1, 0xf, 0xf, false);
          // 16-bit interleave with xor1 partner (explicit bit-ops):
          // even lane j: {mlo.lo16, p1lo.lo16}; odd lane j: {p1lo.hi16, mlo.hi16}
          u32x2 o;
          unsigned ox_e = (mlo & 0xFFFFu) | (p1lo << 16);
          unsigned ox_o = (p1lo >> 16) | (mlo & 0xFFFF0000u);
          unsigned oy_e = (mhi & 0xFFFFu) | (p1hi << 16);
          unsigned oy_o = (p1hi >> 16) | (mhi & 0xFFFF0000u);
          o.x = oddlane ? ox_o : ox_e;
          o.y = oddlane ? oy_o : oy_e;
          *(u32x2*)(xcm + swz4(c0m + jj, p0)) = o;
        }
      }
    }
    __syncthreads();   // B3: X' committed before next mm1
  }
}

extern "C" void kernel_launch(void* const* d_in, const int* in_sizes, int n_in,
                              void* d_out, int out_size, void* d_ws, size_t ws_size,
                              hipStream_t stream) {
  const float* W = (const float*)d_in[0];
  const int* nIt = (const int*)d_in[1];
  float* out = (float*)d_out;
  const int nmat = in_sizes[0] / (NN * NN);   // 1024

  hipFuncSetAttribute((const void*)ns_inverse_kernel,
                      hipFuncAttributeMaxDynamicSharedMemorySize, LDS_BYTES);
  ns_inverse_kernel<<<nmat, 512, LDS_BYTES, stream>>>(W, nIt, out);
}

// Round 12
// 177.590 us; speedup vs baseline: 1.0124x; 1.0124x over previous
//
#include <hip/hip_runtime.h>

// Newton-Schulz batched inverse, 1024 x (128x128) fp32.
// R18: 2 blocks/CU. R17 analysis: MFMA floor 17us, LDS pipe ~50us, rest is
// barrier/latency slack with 1 block/CU in lockstep. Fix: LDS = 80KiB exactly
// -> 2 co-resident blocks overlap each other's barrier drains.
//  - xcm and scr TIME-SHARE one 32KB region (xcs): per iter it holds
//    X^T -> T^T -> X'^T. mm1 pre-reads its B-fragments to regs, band-
//    sequential with 2 extra barriers; all read/write sets disjoint or
//    barrier-separated (5 barriers/iter).
//  - init: 2-pass chunked staging (16KB sheared fp32 chunks). Row/col sums
//    keep the exact serial order -> scale bit-identical; fills/wfrag have
//    identical rounding points.
//  - amdgpu_waves_per_eu(4,4): 16 waves/CU, VGPR cap 128 (live ~105).
// All values/chains identical to R17 -> absmax exactly 9.155273e-5.

#define NN 128

typedef __attribute__((ext_vector_type(8))) short bf16x8;
typedef __attribute__((ext_vector_type(16))) float f32x16;
typedef __attribute__((ext_vector_type(4))) float f32x4;
typedef __attribute__((ext_vector_type(4))) unsigned short us4;
typedef __attribute__((ext_vector_type(2))) unsigned int u32x2;

// LDS layout (bytes):
#define XRM_OFF 0        // X row-major bf16 [0,32768)   (red overlays rows 0..3 in init)
#define XCS_OFF 32768    // X^T / T^T shared region [32768,65536)
#define CHK_OFF 65536    // fp32 sheared 32-row chunk [65536,81920)
#define LDS_BYTES 81920  // exactly half of 160KiB -> 2 blocks/CU

__device__ __forceinline__ unsigned short f2bf(float f) {
  unsigned u = __float_as_uint(f);
  return (unsigned short)((u + 0x7FFFu + ((u >> 16) & 1u)) >> 16);  // RNE
}
__device__ __forceinline__ float bf2f(unsigned short h) {
  return __uint_as_float(((unsigned)h) << 16);
}
__device__ __forceinline__ f32x16 zero16() {
  f32x16 z;
#pragma unroll
  for (int i = 0; i < 16; ++i) z[i] = 0.0f;
  return z;
}
// XOR swizzle in a [R][128] bf16 buffer: 8-elem granule g -> g ^ (R&15).
__device__ __forceinline__ int swz8(int R, int k0) {  // k0 % 8 == 0
  return R * 128 + (((k0 >> 3) ^ (R & 15)) << 3);
}
__device__ __forceinline__ int swz4(int R, int c0) {  // c0 % 4 == 0
  return R * 128 + ((((c0 >> 3) ^ (R & 15)) << 3) | (c0 & 7));
}
// Sheared chunk addressing (f32 index): row rr (0..31), col c (0..127).
// 16B granules rotate by rr -> column reads spread over banks; rows coalesce.
__device__ __forceinline__ int chk_ix(int rr, int c) {
  return rr * 128 + ((((c >> 2) + rr) & 31) << 2) + (c & 3);
}

__global__ void __launch_bounds__(512)
__attribute__((amdgpu_waves_per_eu(4, 4)))
ns_inverse_kernel(const float* __restrict__ Wglob, const int* __restrict__ nIt,
                  float* __restrict__ outglob) {
  extern __shared__ char lds[];
  unsigned short* xrm = (unsigned short*)(lds + XRM_OFF);
  unsigned short* xcs = (unsigned short*)(lds + XCS_OFF);
  float* chk = (float*)(lds + CHK_OFF);
  float* red = (float*)(lds + XRM_OFF);   // init-only, dead before xrm fill

  const int b = blockIdx.x;
  const float* Wg = Wglob + (size_t)b * (NN * NN);
  float* outg = outglob + (size_t)b * (NN * NN);
  const int t = threadIdx.x;  // 0..511
  const int lane = t & 63;
  const int wv = t >> 6;      // 0..7
  const int l31 = lane & 31;
  const int half = lane >> 5;
  const int s = wv & 3;       // strip: W rows (mm1 A) / X' rows (mm2 B, epi)
  const int g = wv >> 2;      // band pair: tiles v0=2g, v1=2g+1
  const int v0 = 2 * g, v1 = 2 * g + 1;
  const int niters = nIt[0];

  // ---- pass 1: chunked norms (exact serial summation order preserved) ----
  float colacc = 0.f;
#pragma unroll
  for (int c = 0; c < 4; ++c) {
    // stage chunk c: W rows [32c..32c+32), coalesced, sheared
#pragma unroll
    for (int i = 0; i < 2; ++i) {
      int idx = t + 512 * i;            // 1024 f32x4
      int rr = idx >> 5, c4 = idx & 31;
      f32x4 v = ((const f32x4*)Wg)[c * 1024 + idx];
      *(f32x4*)(chk + rr * 128 + (((c4 + rr) & 31) << 2)) = v;
    }
    __syncthreads();
    if (t < 128) {
      if ((t >> 5) == c) {              // row t lives in this chunk
        int rr = t & 31;
        float ssum = 0.f;
        for (int jj = 0; jj < 128; ++jj) {   // rotated start, serial (as before)
          int j = (jj + t) & 127;
          ssum += fabsf(chk[chk_ix(rr, j)]);
        }
        red[t] = ssum;
      }
    } else if (t < 256) {               // col sums: i ascending across chunks
      int cc = t - 128;
      float sacc = colacc;
      for (int rr = 0; rr < 32; ++rr) sacc += fabsf(chk[chk_ix(rr, cc)]);
      colacc = sacc;
      if (c == 3) red[128 + cc] = sacc;
    }
    __syncthreads();                    // chunk consumed before restage
  }
  // wave-parallel max reduce (fmax exactly associative+commutative)
  float mA = fmaxf(red[lane], red[lane + 64]);
  float mB = fmaxf(red[128 + lane], red[192 + lane]);
#pragma unroll
  for (int k = 32; k >= 1; k >>= 1) {
    mA = fmaxf(mA, __shfl_xor(mA, k, 64));
    mB = fmaxf(mB, __shfl_xor(mB, k, 64));
  }
  const float scale = 1.0f / (mB * mA);

  // ---- pass 2: chunked fills (red dead after first barrier below) ----
  const int pX = 32 * s + l31;          // lane-owned W row / X/X' row
  bf16x8 wfrag[8];
#pragma unroll
  for (int c = 0; c < 4; ++c) {
#pragma unroll
    for (int i = 0; i < 2; ++i) {       // restage chunk c
      int idx = t + 512 * i;
      int rr = idx >> 5, c4 = idx & 31;
      f32x4 v = ((const f32x4*)Wg)[c * 1024 + idx];
      *(f32x4*)(chk + rr * 128 + (((c4 + rr) & 31) << 2)) = v;
    }
    __syncthreads();                    // also guarantees all red reads done (c==0)
    // X^T rows [32c..32c+32): xcs row r = X0 col r = W row r * scale
    {
      int rr = t >> 4;
      int r = 32 * c + rr;
      int c0 = (t & 15) * 8;
#pragma unroll
      for (int h = 0; h < 2; ++h) {
        int cg = (c0 >> 2) + h;
        f32x4 a = *(const f32x4*)(chk + rr * 128 + (((cg + rr) & 31) << 2));
        us4 hx;
#pragma unroll
        for (int i = 0; i < 4; ++i) hx[i] = f2bf(a[i] * scale);
        *(us4*)(xcs + swz4(r, c0 + 4 * h)) = hx;
      }
    }
    // xrm col-slice [32c..32c+32): xrm[r][32c+rr] = W[32c+rr][r] * scale
    {
      int r = t & 127;
      int rr0 = (t >> 7) * 8;
      us4 h4a, h4b;
#pragma unroll
      for (int k = 0; k < 4; ++k) h4a[k] = f2bf(chk[chk_ix(rr0 + k, r)] * scale);
#pragma unroll
      for (int k = 0; k < 4; ++k) h4b[k] = f2bf(chk[chk_ix(rr0 + 4 + k, r)] * scale);
      *(us4*)(xrm + swz4(r, 32 * c + rr0)) = h4a;
      *(us4*)(xrm + swz4(r, 32 * c + rr0 + 4)) = h4b;
    }
    // wfrag: wave s grabs its W rows from chunk c == s (single bf16 rounding)
    if (s == c) {
      int rr = l31;
#pragma unroll
      for (int ks = 0; ks < 8; ++ks) {
        int cg = 4 * ks + 2 * half;
        f32x4 f0 = *(const f32x4*)(chk + rr * 128 + (((cg + rr) & 31) << 2));
        f32x4 f1 = *(const f32x4*)(chk + rr * 128 + ((((cg + 1) + rr) & 31) << 2));
        bf16x8 wb;
#pragma unroll
        for (int e = 0; e < 4; ++e) {
          wb[e] = (short)f2bf(f0[e]);
          wb[4 + e] = (short)f2bf(f1[e]);
        }
        wfrag[ks] = wb;
      }
    }
    __syncthreads();                    // chunk reads done before restage
  }

  // ---- epilogue transpose constants (lane quads = transpose groups) ----
  const bool oddlane = (lane & 1) != 0;
  const bool swapblk = (lane & 2) != 0;
  const int p0 = 32 * s + (l31 & ~3);
  const int jj = lane & 3;

  // ---------------- iterations: X' = 2X - X(WX) ----------------
  // xcs region per iter: X^T --mm1--> T^T --epi--> X'^T (time-multiplexed).
  // Disjointness: bv0 reads rows {64g..+32} (done at B_a); T0 writes those
  // rows; bv1 reads rows {64g+32..+64} (disjoint from T0 writes); B_b; T1
  // writes rows {64g+32..+64}; B1; mm2 reads all; B2; epi rewrites all; B3.
  const int rv0 = 32 * v0 + l31;
  const int rv1 = 32 * v1 + l31;
  for (int it = 0; it < niters; ++it) {
    const bool last = (it == niters - 1);

    bf16x8 bv[8];
#pragma unroll
    for (int ks = 0; ks < 8; ++ks)
      bv[ks] = *(const bf16x8*)(xcs + swz8(rv0, ks * 16 + half * 8));
    __syncthreads();   // B_a: all band-0 X^T reads complete
    {
      f32x16 tt = zero16();
#pragma unroll
      for (int ks = 0; ks < 8; ++ks)
        tt = __builtin_amdgcn_mfma_f32_32x32x16_bf16(wfrag[ks], bv[ks], tt, 0, 0, 0);
#pragma unroll
      for (int q = 0; q < 4; ++q) {    // T^T tile0 -> rows rv0, cols strip s
        us4 h4;
#pragma unroll
        for (int i = 0; i < 4; ++i) h4[i] = f2bf(tt[4 * q + i]);
        *(us4*)(xcs + swz4(rv0, 32 * s + 8 * q + 4 * half)) = h4;
      }
    }
#pragma unroll
    for (int ks = 0; ks < 8; ++ks)     // band-1 X^T reads (rows untouched yet)
      bv[ks] = *(const bf16x8*)(xcs + swz8(rv1, ks * 16 + half * 8));
    __syncthreads();   // B_b: band-1 reads complete before T1 writes
    {
      f32x16 tt = zero16();
#pragma unroll
      for (int ks = 0; ks < 8; ++ks)
        tt = __builtin_amdgcn_mfma_f32_32x32x16_bf16(wfrag[ks], bv[ks], tt, 0, 0, 0);
#pragma unroll
      for (int q = 0; q < 4; ++q) {    // T^T tile1 -> rows rv1
        us4 h4;
#pragma unroll
        for (int i = 0; i < 4; ++i) h4[i] = f2bf(tt[4 * q + i]);
        *(us4*)(xcs + swz4(rv1, 32 * s + 8 * q + 4 * half)) = h4;
      }
    }
    __syncthreads();   // B1: full T^T assembled

    // mm2: two (X@T)^T tiles; B-frag (xrm row pX) shared
    f32x16 acc0 = zero16(), acc1 = zero16();
#pragma unroll
    for (int ks = 0; ks < 8; ++ks) {
      int k0 = ks * 16 + half * 8;
      bf16x8 bvx = *(const bf16x8*)(xrm + swz8(pX, k0));
      bf16x8 a0 = *(const bf16x8*)(xcs + swz8(rv0, k0));
      bf16x8 a1 = *(const bf16x8*)(xcs + swz8(rv1, k0));
      acc0 = __builtin_amdgcn_mfma_f32_32x32x16_bf16(a0, bvx, acc0, 0, 0, 0);
      acc1 = __builtin_amdgcn_mfma_f32_32x32x16_bf16(a1, bvx, acc1, 0, 0, 0);
    }
    __syncthreads();   // B2: all T^T + xrm reads complete before overwrite

    // epilogue: X'[pX][c] = 2X - (X@T); write xrm row + X'^T into xcs (DPP)
#pragma unroll
    for (int i2 = 0; i2 < 2; ++i2) {
      const int vb = i2 ? v1 : v0;
#pragma unroll
      for (int q = 0; q < 4; ++q) {
        int c0m = 32 * vb + 8 * q + 4 * half;
        int offr = swz4(pX, c0m);
        us4 xh4 = *(const us4*)(xrm + offr);
        f32x4 vv;
#pragma unroll
        for (int i = 0; i < 4; ++i)
          vv[i] = 2.0f * bf2f(xh4[i]) - (i2 ? acc1[4 * q + i] : acc0[4 * q + i]);
        if (last) {
          *(f32x4*)(outg + pX * NN + c0m) = vv;
        } else {
          us4 h4;
#pragma unroll
          for (int i = 0; i < 4; ++i) h4[i] = f2bf(vv[i]);
          *(us4*)(xrm + offr) = h4;          // X' row-major
          // X'^T via in-register 4x4 u16 lane-quad transpose (R17-verified)
          u32x2 d = __builtin_bit_cast(u32x2, h4);
          unsigned lo = d.x, hi = d.y;
          unsigned p2lo = (unsigned)__builtin_amdgcn_mov_dpp((int)lo, 0x4E, 0xf, 0xf, false);
          unsigned p2hi = (unsigned)__builtin_amdgcn_mov_dpp((int)hi, 0x4E, 0xf, 0xf, false);
          unsigned mlo = swapblk ? p2hi : lo;
          unsigned mhi = swapblk ? hi   : p2lo;
          unsigned p1lo = (unsigned)__builtin_amdgcn_mov_dpp((int)mlo, 0xB1, 0xf, 0xf, false);
          unsigned p1hi = (unsigned)__builtin_amdgcn_mov_dpp((int)mhi, 0xB1, 0xf, 0xf, false);
          u32x2 o;
          unsigned ox_e = (mlo & 0xFFFFu) | (p1lo << 16);
          unsigned ox_o = (p1lo >> 16) | (mlo & 0xFFFF0000u);
          unsigned oy_e = (mhi & 0xFFFFu) | (p1hi << 16);
          unsigned oy_o = (p1hi >> 16) | (mhi & 0xFFFF0000u);
          o.x = oddlane ? ox_o : ox_e;
          o.y = oddlane ? oy_o : oy_e;
          *(u32x2*)(xcs + swz4(c0m + jj, p0)) = o;
        }
      }
    }
    __syncthreads();   // B3: X' committed before next iter's bv0 reads
  }
}

extern "C" void kernel_launch(void* const* d_in, const int* in_sizes, int n_in,
                              void* d_out, int out_size, void* d_ws, size_t ws_size,
                              hipStream_t stream) {
  const float* W = (const float*)d_in[0];
  const int* nIt = (const int*)d_in[1];
  float* out = (float*)d_out;
  const int nmat = in_sizes[0] / (NN * NN);  // 1024

  hipFuncSetAttribute((const void*)ns_inverse_kernel,
                      hipFuncAttributeMaxDynamicSharedMemorySize, LDS_BYTES);
  ns_inverse_kernel<<<nmat, 512, LDS_BYTES, stream>>>(W, nIt, out);
}